// Round 2
// baseline (6100.110 us; speedup 1.0000x reference)
//
#include <hip/hip_runtime.h>
#include <hip/hip_bf16.h>
#include <math.h>

// Problem constants
#define NB   2
#define CIN  256
#define CC   512
#define GG   8
#define CGR  64     // channels per group
#define HH   48
#define WW   48
#define PP   (HH*WW)        // 2304
#define HD   46
#define WD   46
#define DD   (HD*WD)        // 2116
#define DSPLIT 529          // 4*529 = 2116 (per-wave D range)
#define CHUNK 8

__device__ __forceinline__ float bf16lo(uint32_t u) { return __uint_as_float(u << 16); }
__device__ __forceinline__ float bf16hi(uint32_t u) { return __uint_as_float(u & 0xffff0000u); }

// ---------------------------------------------------------------------------
// Kernel 1: x = W_x * x_in + W_ig * h ; write interleaved xh (bf16)
// xh layout: [n][g][128][p] where ch 0..63 = x group g, 64..127 = h group g
// grid (9, 512, 2), block 256
// ---------------------------------------------------------------------------
__global__ __launch_bounds__(256) void proj_kernel(
    const float* __restrict__ x_in, const float* __restrict__ h,
    const float* __restrict__ W_x, const float* __restrict__ W_ig,
    __hip_bfloat16* __restrict__ xh)
{
    const int c = blockIdx.y;
    const int n = blockIdx.z;
    const int p = blockIdx.x * 256 + threadIdx.x;   // 9*256 = 2304 exact
    const int g = c >> 6, cg = c & 63;

    const float* xi  = x_in + (size_t)n * CIN * PP;
    const float* hp  = h    + (size_t)n * CC  * PP;
    const float* wx  = W_x  + (size_t)c * CIN;
    const float* wig = W_ig + (size_t)c * CC;

    float a0 = 0.f, a1 = 0.f, a2 = 0.f, a3 = 0.f;
    for (int i = 0; i < CIN; i += 4) {
        a0 += wx[i]   * xi[(size_t)i    * PP + p];
        a1 += wx[i+1] * xi[(size_t)(i+1)* PP + p];
        a2 += wx[i+2] * xi[(size_t)(i+2)* PP + p];
        a3 += wx[i+3] * xi[(size_t)(i+3)* PP + p];
    }
    for (int i = 0; i < CC; i += 4) {
        a0 += wig[i]   * hp[(size_t)i    * PP + p];
        a1 += wig[i+1] * hp[(size_t)(i+1)* PP + p];
        a2 += wig[i+2] * hp[(size_t)(i+2)* PP + p];
        a3 += wig[i+3] * hp[(size_t)(i+3)* PP + p];
    }
    float acc = (a0 + a1) + (a2 + a3);

    __hip_bfloat16* dst = xh + ((size_t)(n * GG + g) * 128) * PP;
    dst[(size_t)cg       * PP + p] = (__hip_bfloat16)acc;
    dst[(size_t)(64 + cg)* PP + p] = (__hip_bfloat16)hp[(size_t)c * PP + p];
}

// ---------------------------------------------------------------------------
// Kernel 2: grouped 3x3 conv on xh (bf16 in, bf16 out, fp32 accumulate).
// transposed==0: out[ng][cg][p] (q). transposed==1: out[ng][p][cg] (k,v)
// grid (ceil(oP/256), 512, 2), block 256
// ---------------------------------------------------------------------------
__global__ __launch_bounds__(256) void grouped_conv3_kernel(
    const __hip_bfloat16* __restrict__ xh, const float* __restrict__ Wt,
    __hip_bfloat16* __restrict__ out, int pad, int oh, int ow, int transposed)
{
    const int co = blockIdx.y;
    const int n  = blockIdx.z;
    const int g  = co >> 6, cg = co & 63;
    const int oP = oh * ow;
    const int p  = blockIdx.x * 256 + threadIdx.x;
    if (p >= oP) return;
    const int y = p / ow, x = p % ow;

    const __hip_bfloat16* src = xh + ((size_t)(n * GG + g) * 128) * PP;
    const float* w = Wt + (size_t)co * 128 * 9;

    float acc = 0.f;
    for (int ci = 0; ci < 128; ++ci) {
        const __hip_bfloat16* s = src + (size_t)ci * PP;
        const float* wc = w + ci * 9;
        #pragma unroll
        for (int ky = 0; ky < 3; ++ky) {
            const int iy = y + ky - pad;
            if (iy < 0 || iy >= HH) continue;
            #pragma unroll
            for (int kx = 0; kx < 3; ++kx) {
                const int ix = x + kx - pad;
                if (ix < 0 || ix >= WW) continue;
                acc += wc[ky*3 + kx] * (float)s[iy*WW + ix];
            }
        }
    }
    const int ng = n * GG + g;
    if (transposed)
        out[((size_t)ng * DD + p) * CGR + cg] = (__hip_bfloat16)acc;
    else
        out[((size_t)ng * CGR + cg) * (size_t)oP + p] = (__hip_bfloat16)acc;
}

// ---------------------------------------------------------------------------
// Kernel 3: flash attention, block-cooperative. One block = 64 q-rows;
// 4 waves split D (529 each); merge via LDS; writes final a (bf16) directly.
// q: [ng][cg][2304] bf16, kT/vT: [ng][d][64] bf16, a aliases q's buffer.
// grid (36, 16), block 256
// ---------------------------------------------------------------------------
__global__ __launch_bounds__(256) void attn_kernel(
    const __hip_bfloat16* __restrict__ q, const __hip_bfloat16* __restrict__ kT,
    const __hip_bfloat16* __restrict__ vT, const float* __restrict__ tau,
    __hip_bfloat16* __restrict__ a)
{
    const int ng   = blockIdx.y;           // 0..15
    const int qt   = blockIdx.x;           // 0..35
    const int tid  = threadIdx.x;
    const int lane = tid & 63;             // q-row within tile
    const int w    = tid >> 6;             // wave id 0..3 (D-split)
    const int qp   = qt * 64 + lane;
    const float t  = tau[ng & 7];

    __shared__ float sm[4 * 64];
    __shared__ float sl[4 * 64];
    __shared__ float accbuf[64 * 65];      // +1 pad: 2-way bank alias only

    // Load this lane's q row, scaled by tau
    const __hip_bfloat16* qb = q + (size_t)ng * CGR * PP + qp;
    float qreg[CGR];
    #pragma unroll
    for (int i = 0; i < CGR; ++i) qreg[i] = t * (float)qb[(size_t)i * PP];

    const size_t kb = (size_t)ng * DD * CGR;
    float m = -INFINITY, l = 0.f;
    float acc[CGR];
    #pragma unroll
    for (int i = 0; i < CGR; ++i) acc[i] = 0.f;

    const int d0 = w * DSPLIT;
    for (int cc = 0; cc < DSPLIT; cc += CHUNK) {
        float lg[CHUNK];
        #pragma unroll
        for (int j = 0; j < CHUNK; ++j) {
            const bool valid = (cc + j) < DSPLIT;
            int d = d0 + cc + j;
            if (d > DD - 1) d = DD - 1;
            d = __builtin_amdgcn_readfirstlane(d);
            const uint32_t* kr = (const uint32_t*)(kT + kb + (size_t)d * CGR);
            float s0 = 0.f, s1 = 0.f, s2 = 0.f, s3 = 0.f;
            #pragma unroll
            for (int i = 0; i < 32; i += 2) {
                const uint32_t p0 = kr[i], p1 = kr[i+1];
                s0 += qreg[2*i]   * bf16lo(p0);
                s1 += qreg[2*i+1] * bf16hi(p0);
                s2 += qreg[2*i+2] * bf16lo(p1);
                s3 += qreg[2*i+3] * bf16hi(p1);
            }
            lg[j] = valid ? ((s0 + s1) + (s2 + s3)) : -1e30f;
        }
        float mnew = m;
        #pragma unroll
        for (int j = 0; j < CHUNK; ++j) mnew = fmaxf(mnew, lg[j]);
        const float alpha = __expf(m - mnew);      // first chunk: exp(-inf)=0
        m = mnew;
        float lsum = 0.f;
        #pragma unroll
        for (int j = 0; j < CHUNK; ++j) {
            lg[j] = __expf(lg[j] - mnew);          // 0 for masked entries
            lsum += lg[j];
        }
        l = l * alpha + lsum;
        #pragma unroll
        for (int i = 0; i < CGR; ++i) acc[i] *= alpha;
        #pragma unroll
        for (int j = 0; j < CHUNK; ++j) {
            int d = d0 + cc + j;
            if (d > DD - 1) d = DD - 1;
            d = __builtin_amdgcn_readfirstlane(d);
            const uint32_t* vr = (const uint32_t*)(vT + kb + (size_t)d * CGR);
            const float wj = lg[j];
            #pragma unroll
            for (int i = 0; i < 32; ++i) {
                const uint32_t pv = vr[i];
                acc[2*i]   += wj * bf16lo(pv);
                acc[2*i+1] += wj * bf16hi(pv);
            }
        }
    }

    // ---- merge the 4 D-splits through LDS ----
    sm[w * 64 + lane] = m;
    for (int idx = tid; idx < 64 * 65; idx += 256) accbuf[idx] = 0.f;
    __syncthreads();
    const float mstar = fmaxf(fmaxf(sm[lane], sm[64 + lane]),
                              fmaxf(sm[128 + lane], sm[192 + lane]));
    const float scale = __expf(m - mstar);
    sl[w * 64 + lane] = l * scale;
    #pragma unroll
    for (int i = 0; i < CGR; ++i)
        atomicAdd(&accbuf[lane * 65 + i], acc[i] * scale);
    __syncthreads();

    for (int idx = tid; idx < 64 * 64; idx += 256) {
        const int row = idx & 63, cg = idx >> 6;
        const float Lr = sl[row] + sl[64 + row] + sl[128 + row] + sl[192 + row];
        a[((size_t)ng * CGR + cg) * PP + qt * 64 + row] =
            (__hip_bfloat16)(accbuf[row * 65 + cg] / Lr);
    }
}

// ---------------------------------------------------------------------------
// Kernel 4: fused gates + LSTM update. a is bf16 [ng][cg][p] (aliases q buf).
// grid (9, 512, 2), block 256
// ---------------------------------------------------------------------------
__global__ __launch_bounds__(256) void gates_kernel(
    const __hip_bfloat16* __restrict__ xh, const __hip_bfloat16* __restrict__ a_in,
    const float* __restrict__ c_in,
    const float* __restrict__ Wi_a, const float* __restrict__ Wi_x, const float* __restrict__ b_i,
    const float* __restrict__ Wf_a, const float* __restrict__ Wf_x, const float* __restrict__ b_f,
    const float* __restrict__ Wg_a, const float* __restrict__ Wg_x, const float* __restrict__ b_g,
    const float* __restrict__ Wo_a, const float* __restrict__ Wo_x, const float* __restrict__ b_o,
    float* __restrict__ h_out)
{
    const int c = blockIdx.y;
    const int n = blockIdx.z;
    const int p = blockIdx.x * 256 + threadIdx.x;
    const int g = c >> 6;
    const int y = p / WW, x = p % WW;

    float ai = b_i[c], af = b_f[c], ag = b_g[c], ao = b_o[c];

    // 1x1 grouped conv on a
    const __hip_bfloat16* ab = a_in + ((size_t)(n * GG + g) * CGR) * PP + p;
    const float* wia = Wi_a + (size_t)c * CGR;
    const float* wfa = Wf_a + (size_t)c * CGR;
    const float* wga = Wg_a + (size_t)c * CGR;
    const float* woa = Wo_a + (size_t)c * CGR;
    for (int j = 0; j < CGR; ++j) {
        const float av = (float)ab[(size_t)j * PP];
        ai += wia[j] * av;
        af += wfa[j] * av;
        ag += wga[j] * av;
        ao += woa[j] * av;
    }

    // 3x3 grouped conv on xh (pad=1)
    const __hip_bfloat16* src = xh + ((size_t)(n * GG + g) * 128) * PP;
    const float* wix = Wi_x + (size_t)c * 1152;
    const float* wfx = Wf_x + (size_t)c * 1152;
    const float* wgx = Wg_x + (size_t)c * 1152;
    const float* wox = Wo_x + (size_t)c * 1152;
    for (int ci = 0; ci < 128; ++ci) {
        const __hip_bfloat16* s = src + (size_t)ci * PP;
        const int wb = ci * 9;
        #pragma unroll
        for (int ky = 0; ky < 3; ++ky) {
            const int iy = y + ky - 1;
            if (iy < 0 || iy >= HH) continue;
            #pragma unroll
            for (int kx = 0; kx < 3; ++kx) {
                const int ix = x + kx - 1;
                if (ix < 0 || ix >= WW) continue;
                const float xv = (float)s[iy*WW + ix];
                const int wi = wb + ky*3 + kx;
                ai += wix[wi] * xv;
                af += wfx[wi] * xv;
                ag += wgx[wi] * xv;
                ao += wox[wi] * xv;
            }
        }
    }

    const float ig = 1.f / (1.f + __expf(-ai));
    const float fg = 1.f / (1.f + __expf(-af));
    const float gv = tanhf(ag);
    const float og = 1.f / (1.f + __expf(-ao));
    const float cv = c_in[((size_t)n * CC + c) * PP + p];
    const float cn = fg * cv + ig * gv;
    h_out[((size_t)n * CC + c) * PP + p] = og * tanhf(cn);
}

// ---------------------------------------------------------------------------
extern "C" void kernel_launch(void* const* d_in, const int* in_sizes, int n_in,
                              void* d_out, int out_size, void* d_ws, size_t ws_size,
                              hipStream_t stream)
{
    const float* x_in = (const float*)d_in[0];
    const float* h    = (const float*)d_in[1];
    const float* c    = (const float*)d_in[2];
    const float* tau  = (const float*)d_in[3];
    const float* W_x  = (const float*)d_in[4];
    const float* W_ig = (const float*)d_in[5];
    const float* W_q  = (const float*)d_in[6];
    const float* W_k  = (const float*)d_in[7];
    const float* W_v  = (const float*)d_in[8];
    const float* Wi_a = (const float*)d_in[9];
    const float* Wi_x = (const float*)d_in[10];
    const float* b_i  = (const float*)d_in[11];
    const float* Wf_a = (const float*)d_in[12];
    const float* Wf_x = (const float*)d_in[13];
    const float* b_f  = (const float*)d_in[14];
    const float* Wg_a = (const float*)d_in[15];
    const float* Wg_x = (const float*)d_in[16];
    const float* b_g  = (const float*)d_in[17];
    const float* Wo_a = (const float*)d_in[18];
    const float* Wo_x = (const float*)d_in[19];
    const float* b_o  = (const float*)d_in[20];
    float* out = (float*)d_out;

    // Workspace: ALL bf16, total 22,822,912 bytes (~21.8 MB).
    __hip_bfloat16* wsb = (__hip_bfloat16*)d_ws;
    __hip_bfloat16* xh = wsb;                         // 4,718,592 elems
    __hip_bfloat16* qa = xh + (size_t)4718592;        // 2,359,296 (q, then a)
    __hip_bfloat16* kT = qa + (size_t)2359296;        // 2,166,784
    __hip_bfloat16* vT = kT + (size_t)2166784;        // 2,166,784

    dim3 blk(256);
    proj_kernel<<<dim3(9, CC, NB), blk, 0, stream>>>(x_in, h, W_x, W_ig, xh);
    grouped_conv3_kernel<<<dim3(9, CC, NB), blk, 0, stream>>>(xh, W_q, qa, 1, HH, WW, 0);
    grouped_conv3_kernel<<<dim3(9, CC, NB), blk, 0, stream>>>(xh, W_k, kT, 0, HD, WD, 1);
    grouped_conv3_kernel<<<dim3(9, CC, NB), blk, 0, stream>>>(xh, W_v, vT, 0, HD, WD, 1);
    attn_kernel<<<dim3(36, 16), blk, 0, stream>>>(qa, kT, vT, tau, qa);
    gates_kernel<<<dim3(9, CC, NB), blk, 0, stream>>>(
        xh, qa, c, Wi_a, Wi_x, b_i, Wf_a, Wf_x, b_f,
        Wg_a, Wg_x, b_g, Wo_a, Wo_x, b_o, out);
}

// Round 3
// 4079.315 us; speedup vs baseline: 1.4954x; 1.4954x over previous
//
#include <hip/hip_runtime.h>
#include <hip/hip_bf16.h>
#include <math.h>

// Problem constants
#define NB   2
#define CIN  256
#define CC   512
#define GG   8
#define CGR  64     // channels per group
#define HH   48
#define WW   48
#define PP   (HH*WW)        // 2304
#define HD   46
#define WD   46
#define DD   (HD*WD)        // 2116
#define DPADV 2120          // v row stride (multiple of 8 -> 16B aligned rows)

typedef __bf16 bf16x8 __attribute__((ext_vector_type(8)));
typedef float  f32x4  __attribute__((ext_vector_type(4)));

__device__ __forceinline__ float bf16lo(uint32_t u) { return __uint_as_float(u << 16); }
__device__ __forceinline__ float bf16hi(uint32_t u) { return __uint_as_float(u & 0xffff0000u); }
__device__ __forceinline__ bf16x8 ldb8(const __hip_bfloat16* p) {
    return *reinterpret_cast<const bf16x8*>(p);
}

// ---------------------------------------------------------------------------
// Kernel 1: x = W_x * x_in + W_ig * h ; write interleaved xh (bf16)
// xh layout: [n][g][128][p], ch 0..63 = x group g, 64..127 = h group g
// grid (9, 512, 2), block 256
// ---------------------------------------------------------------------------
__global__ __launch_bounds__(256) void proj_kernel(
    const float* __restrict__ x_in, const float* __restrict__ h,
    const float* __restrict__ W_x, const float* __restrict__ W_ig,
    __hip_bfloat16* __restrict__ xh)
{
    const int c = blockIdx.y;
    const int n = blockIdx.z;
    const int p = blockIdx.x * 256 + threadIdx.x;
    const int g = c >> 6, cg = c & 63;

    const float* xi  = x_in + (size_t)n * CIN * PP;
    const float* hp  = h    + (size_t)n * CC  * PP;
    const float* wx  = W_x  + (size_t)c * CIN;
    const float* wig = W_ig + (size_t)c * CC;

    float a0 = 0.f, a1 = 0.f, a2 = 0.f, a3 = 0.f;
    for (int i = 0; i < CIN; i += 4) {
        a0 += wx[i]   * xi[(size_t)i    * PP + p];
        a1 += wx[i+1] * xi[(size_t)(i+1)* PP + p];
        a2 += wx[i+2] * xi[(size_t)(i+2)* PP + p];
        a3 += wx[i+3] * xi[(size_t)(i+3)* PP + p];
    }
    for (int i = 0; i < CC; i += 4) {
        a0 += wig[i]   * hp[(size_t)i    * PP + p];
        a1 += wig[i+1] * hp[(size_t)(i+1)* PP + p];
        a2 += wig[i+2] * hp[(size_t)(i+2)* PP + p];
        a3 += wig[i+3] * hp[(size_t)(i+3)* PP + p];
    }
    float acc = (a0 + a1) + (a2 + a3);

    __hip_bfloat16* dst = xh + ((size_t)(n * GG + g) * 128) * PP;
    dst[(size_t)cg       * PP + p] = (__hip_bfloat16)acc;
    dst[(size_t)(64 + cg)* PP + p] = (__hip_bfloat16)hp[(size_t)c * PP + p];
}

// ---------------------------------------------------------------------------
// Kernel 2: grouped 3x3 conv on xh (bf16 in/out, fp32 acc). XCD-swizzled 1D
// grid (9216 blocks): idx&7 = group (L2 locality on the shared xh slab).
// transposed: out[(ng*ostride + p)*64 + cg]   (q: ostride=2304, k: 2116)
// planar:     out[(ng*64+cg)*ostride + p]     (v: ostride=2120)
// ---------------------------------------------------------------------------
__global__ __launch_bounds__(256) void grouped_conv3_kernel(
    const __hip_bfloat16* __restrict__ xh, const float* __restrict__ Wt,
    __hip_bfloat16* __restrict__ out, int pad, int oh, int ow,
    int transposed, int ostride)
{
    const int idx = blockIdx.x;
    const int g   = idx & 7;
    const int j   = idx >> 3;            // 0..1151
    const int n   = (j >= 576) ? 1 : 0;
    const int local = j - n * 576;       // 0..575
    const int cg  = local & 63;
    const int px  = local >> 6;          // 0..8
    const int co  = g * 64 + cg;

    const int oP = oh * ow;
    const int p  = px * 256 + threadIdx.x;
    if (p >= oP) return;
    const int y = p / ow, x = p % ow;

    const __hip_bfloat16* src = xh + ((size_t)(n * GG + g) * 128) * PP;
    const float* w = Wt + (size_t)co * 128 * 9;

    float acc = 0.f;
    for (int ci = 0; ci < 128; ++ci) {
        const __hip_bfloat16* s = src + (size_t)ci * PP;
        const float* wc = w + ci * 9;
        #pragma unroll
        for (int ky = 0; ky < 3; ++ky) {
            const int iy = y + ky - pad;
            if (iy < 0 || iy >= HH) continue;
            #pragma unroll
            for (int kx = 0; kx < 3; ++kx) {
                const int ix = x + kx - pad;
                if (ix < 0 || ix >= WW) continue;
                acc += wc[ky*3 + kx] * (float)s[iy*WW + ix];
            }
        }
    }
    const int ng = n * GG + g;
    if (transposed)
        out[((size_t)ng * ostride + p) * CGR + cg] = (__hip_bfloat16)acc;
    else
        out[(size_t)(ng * CGR + cg) * ostride + p] = (__hip_bfloat16)acc;
}

// ---------------------------------------------------------------------------
// Kernel 3: MFMA flash attention. One wave = 16 q columns, full D sweep.
// Computes S^T = K^T x Q (so softmax stats are per-lane scalars), then
// O^T = V x P^T. qa: qT [ng][2304][64] read, aT [ng][2304][64] written
// (same buffer; each lane writes exactly the rows it read).
// kT: [ng][2116][64], v: [ng][64][2120]. grid 576 blocks x 256.
// ---------------------------------------------------------------------------
__global__ __launch_bounds__(256) void attn_kernel(
    __hip_bfloat16* qa,                      // qT in, aT out (aliased!)
    const __hip_bfloat16* __restrict__ kT,
    const __hip_bfloat16* __restrict__ vT,
    const float* __restrict__ tau)
{
    const int idx = blockIdx.x;              // 0..575, idx&7 = group
    const int j3  = idx >> 3;                // 0..71
    const int ng  = (idx & 7) + ((j3 >= 36) ? 8 : 0);
    const int qt  = j3 - ((j3 >= 36) ? 36 : 0);     // 0..35
    const int tid  = threadIdx.x;
    const int w    = tid >> 6;
    const int lane = tid & 63;
    const int col  = lane & 15;              // q within tile / c within 16
    const int quad = lane >> 4;
    const int qbase = qt * 64 + w * 16;
    const float t = tau[ng & 7];

    // Q B-frags (persistent): B[k=c][n=q], lane holds c = ks*32 + quad*8 + j
    __hip_bfloat16* qrow = qa + ((size_t)ng * PP + qbase + col) * CGR;
    const bf16x8 qf0 = ldb8(qrow + quad * 8);
    const bf16x8 qf1 = ldb8(qrow + 32 + quad * 8);

    const __hip_bfloat16* kbase = kT + (size_t)ng * DD * CGR;
    const __hip_bfloat16* vbase = vT + (size_t)ng * CGR * DPADV;

    f32x4 acc[4];
    #pragma unroll
    for (int cf = 0; cf < 4; ++cf) acc[cf] = (f32x4){0.f, 0.f, 0.f, 0.f};
    float m = -INFINITY, l = 0.f;
    const f32x4 zero = {0.f, 0.f, 0.f, 0.f};

    for (int dbase = 0; dbase < 2144; dbase += 32) {
        // ---- S^T tiles: two 16-d frags, K = 64 channels (2 mfma each) ----
        const int dr0 = min(dbase + col,      DD - 1);
        const int dr1 = min(dbase + 16 + col, DD - 1);
        const __hip_bfloat16* k0 = kbase + (size_t)dr0 * CGR + quad * 8;
        const __hip_bfloat16* k1 = kbase + (size_t)dr1 * CGR + quad * 8;
        f32x4 S0 = __builtin_amdgcn_mfma_f32_16x16x32_bf16(ldb8(k0), qf0, zero, 0, 0, 0);
        S0 = __builtin_amdgcn_mfma_f32_16x16x32_bf16(ldb8(k0 + 32), qf1, S0, 0, 0, 0);
        f32x4 S1 = __builtin_amdgcn_mfma_f32_16x16x32_bf16(ldb8(k1), qf0, zero, 0, 0, 0);
        S1 = __builtin_amdgcn_mfma_f32_16x16x32_bf16(ldb8(k1 + 32), qf1, S1, 0, 0, 0);

        // ---- scale by tau, mask invalid keys ----
        float p0[4], p1[4];
        #pragma unroll
        for (int r = 0; r < 4; ++r) {
            const int d0v = dbase + quad * 4 + r;
            const int d1v = dbase + 16 + quad * 4 + r;
            p0[r] = (d0v < DD) ? S0[r] * t : -1e30f;
            p1[r] = (d1v < DD) ? S1[r] * t : -1e30f;
        }

        // ---- online softmax (per column q = per lane) ----
        float smax = fmaxf(fmaxf(fmaxf(p0[0], p0[1]), fmaxf(p0[2], p0[3])),
                           fmaxf(fmaxf(p1[0], p1[1]), fmaxf(p1[2], p1[3])));
        smax = fmaxf(smax, __shfl_xor(smax, 16, 64));
        smax = fmaxf(smax, __shfl_xor(smax, 32, 64));
        const float mnew = fmaxf(m, smax);
        const float alpha = __expf(m - mnew);
        float lsum = 0.f;
        #pragma unroll
        for (int r = 0; r < 4; ++r) {
            p0[r] = __expf(p0[r] - mnew);
            p1[r] = __expf(p1[r] - mnew);
            lsum += p0[r] + p1[r];
        }
        lsum += __shfl_xor(lsum, 16, 64);
        lsum += __shfl_xor(lsum, 32, 64);
        l = l * alpha + lsum;
        m = mnew;
        #pragma unroll
        for (int cf = 0; cf < 4; ++cf)
            acc[cf] *= alpha;

        // ---- build P^T B-frag: B[k=d_local=quad*8+j][n=q=col] ----
        bf16x8 pt;
        #pragma unroll
        for (int jj = 0; jj < 8; ++jj) {
            const int srcLane = ((((quad & 1) * 2 + (jj >> 2)) << 4) | col);
            const float v0 = __shfl(p0[jj & 3], srcLane, 64);
            const float v1 = __shfl(p1[jj & 3], srcLane, 64);
            pt[jj] = (__bf16)((quad >= 2) ? v1 : v0);
        }

        // ---- O^T += V * P^T (4 c-frags of 16) ----
        const int dv = min(dbase + quad * 8, DD - 4);   // clamp: masked rows only
        #pragma unroll
        for (int cf = 0; cf < 4; ++cf) {
            const __hip_bfloat16* vp = vbase + (size_t)(cf * 16 + col) * DPADV + dv;
            acc[cf] = __builtin_amdgcn_mfma_f32_16x16x32_bf16(ldb8(vp), pt, acc[cf], 0, 0, 0);
        }
    }

    // ---- epilogue: normalize, write aT (same rows this lane read) ----
    const float inv = 1.f / l;
    __hip_bfloat16* arow = qa + ((size_t)ng * PP + qbase + col) * CGR;
    #pragma unroll
    for (int cf = 0; cf < 4; ++cf)
        #pragma unroll
        for (int r = 0; r < 4; ++r)
            arow[cf * 16 + quad * 4 + r] = (__hip_bfloat16)(acc[cf][r] * inv);
}

// ---------------------------------------------------------------------------
// Kernel 4: fused gates + LSTM update. XCD-swizzled 1D grid (9216).
// a is bf16 aT [ng][p][64].
// ---------------------------------------------------------------------------
__global__ __launch_bounds__(256) void gates_kernel(
    const __hip_bfloat16* __restrict__ xh, const __hip_bfloat16* __restrict__ aT,
    const float* __restrict__ c_in,
    const float* __restrict__ Wi_a, const float* __restrict__ Wi_x, const float* __restrict__ b_i,
    const float* __restrict__ Wf_a, const float* __restrict__ Wf_x, const float* __restrict__ b_f,
    const float* __restrict__ Wg_a, const float* __restrict__ Wg_x, const float* __restrict__ b_g,
    const float* __restrict__ Wo_a, const float* __restrict__ Wo_x, const float* __restrict__ b_o,
    float* __restrict__ h_out)
{
    const int idx = blockIdx.x;
    const int g   = idx & 7;
    const int j   = idx >> 3;
    const int n   = (j >= 576) ? 1 : 0;
    const int local = j - n * 576;
    const int cg  = local & 63;
    const int px  = local >> 6;
    const int c   = g * 64 + cg;
    const int p   = px * 256 + threadIdx.x;
    const int y = p / WW, x = p % WW;

    float ai = b_i[c], af = b_f[c], ag = b_g[c], ao = b_o[c];

    // 1x1 grouped conv on a (aT rows are contiguous 64 bf16)
    const uint32_t* ap = (const uint32_t*)(aT + ((size_t)(n * GG + g) * PP + p) * CGR);
    const float* wia = Wi_a + (size_t)c * CGR;
    const float* wfa = Wf_a + (size_t)c * CGR;
    const float* wga = Wg_a + (size_t)c * CGR;
    const float* woa = Wo_a + (size_t)c * CGR;
    #pragma unroll 8
    for (int jj = 0; jj < 32; ++jj) {
        const uint32_t u = ap[jj];
        const float alo = bf16lo(u), ahi = bf16hi(u);
        ai += wia[2*jj] * alo + wia[2*jj+1] * ahi;
        af += wfa[2*jj] * alo + wfa[2*jj+1] * ahi;
        ag += wga[2*jj] * alo + wga[2*jj+1] * ahi;
        ao += woa[2*jj] * alo + woa[2*jj+1] * ahi;
    }

    // 3x3 grouped conv on xh (pad=1)
    const __hip_bfloat16* src = xh + ((size_t)(n * GG + g) * 128) * PP;
    const float* wix = Wi_x + (size_t)c * 1152;
    const float* wfx = Wf_x + (size_t)c * 1152;
    const float* wgx = Wg_x + (size_t)c * 1152;
    const float* wox = Wo_x + (size_t)c * 1152;
    for (int ci = 0; ci < 128; ++ci) {
        const __hip_bfloat16* s = src + (size_t)ci * PP;
        const int wb = ci * 9;
        #pragma unroll
        for (int ky = 0; ky < 3; ++ky) {
            const int iy = y + ky - 1;
            if (iy < 0 || iy >= HH) continue;
            #pragma unroll
            for (int kx = 0; kx < 3; ++kx) {
                const int ix = x + kx - 1;
                if (ix < 0 || ix >= WW) continue;
                const float xv = (float)s[iy*WW + ix];
                const int wi = wb + ky*3 + kx;
                ai += wix[wi] * xv;
                af += wfx[wi] * xv;
                ag += wgx[wi] * xv;
                ao += wox[wi] * xv;
            }
        }
    }

    const float ig = 1.f / (1.f + __expf(-ai));
    const float fg = 1.f / (1.f + __expf(-af));
    const float gv = tanhf(ag);
    const float og = 1.f / (1.f + __expf(-ao));
    const float cv = c_in[((size_t)n * CC + c) * PP + p];
    const float cn = fg * cv + ig * gv;
    h_out[((size_t)n * CC + c) * PP + p] = og * tanhf(cn);
}

// ---------------------------------------------------------------------------
extern "C" void kernel_launch(void* const* d_in, const int* in_sizes, int n_in,
                              void* d_out, int out_size, void* d_ws, size_t ws_size,
                              hipStream_t stream)
{
    const float* x_in = (const float*)d_in[0];
    const float* h    = (const float*)d_in[1];
    const float* c    = (const float*)d_in[2];
    const float* tau  = (const float*)d_in[3];
    const float* W_x  = (const float*)d_in[4];
    const float* W_ig = (const float*)d_in[5];
    const float* W_q  = (const float*)d_in[6];
    const float* W_k  = (const float*)d_in[7];
    const float* W_v  = (const float*)d_in[8];
    const float* Wi_a = (const float*)d_in[9];
    const float* Wi_x = (const float*)d_in[10];
    const float* b_i  = (const float*)d_in[11];
    const float* Wf_a = (const float*)d_in[12];
    const float* Wf_x = (const float*)d_in[13];
    const float* b_f  = (const float*)d_in[14];
    const float* Wg_a = (const float*)d_in[15];
    const float* Wg_x = (const float*)d_in[16];
    const float* b_g  = (const float*)d_in[17];
    const float* Wo_a = (const float*)d_in[18];
    const float* Wo_x = (const float*)d_in[19];
    const float* b_o  = (const float*)d_in[20];
    float* out = (float*)d_out;

    // Workspace (bf16): total 22,831,104 bytes
    __hip_bfloat16* wsb = (__hip_bfloat16*)d_ws;
    __hip_bfloat16* xh = wsb;                       // 4,718,592 elems
    __hip_bfloat16* qa = xh + (size_t)4718592;      // 2,359,296 (qT, then aT)
    __hip_bfloat16* kT = qa + (size_t)2359296;      // 2,166,784
    __hip_bfloat16* vv = kT + (size_t)2166784;      // 2,170,880 (stride 2120)

    dim3 blk(256);
    proj_kernel<<<dim3(9, CC, NB), blk, 0, stream>>>(x_in, h, W_x, W_ig, xh);
    grouped_conv3_kernel<<<dim3(9216), blk, 0, stream>>>(xh, W_q, qa, 1, HH, WW, 1, PP);
    grouped_conv3_kernel<<<dim3(9216), blk, 0, stream>>>(xh, W_k, kT, 0, HD, WD, 1, DD);
    grouped_conv3_kernel<<<dim3(9216), blk, 0, stream>>>(xh, W_v, vv, 0, HD, WD, 0, DPADV);
    attn_kernel<<<dim3(576), blk, 0, stream>>>(qa, kT, vv, tau);
    gates_kernel<<<dim3(9216), blk, 0, stream>>>(
        xh, qa, c, Wi_a, Wi_x, b_i, Wf_a, Wf_x, b_f,
        Wg_a, Wg_x, b_g, Wo_a, Wo_x, b_o, out);
}

// Round 4
// 571.981 us; speedup vs baseline: 10.6649x; 7.1319x over previous
//
#include <hip/hip_runtime.h>
#include <hip/hip_bf16.h>
#include <math.h>

// Problem constants
#define NB   2
#define CIN  256
#define CC   512
#define GG   8
#define CGR  64
#define HH   48
#define WW   48
#define PP   (HH*WW)        // 2304
#define HD   46
#define WD   46
#define DD   (HD*WD)        // 2116
#define DPADV 2120          // v row stride (16B-aligned rows)
#define WRT  589824         // 512*9*128, per-tensor reordered weight stride

typedef __bf16 bf16x8 __attribute__((ext_vector_type(8)));
typedef float  f32x4  __attribute__((ext_vector_type(4)));

__device__ __forceinline__ bf16x8 ldb8(const __hip_bfloat16* p) {
    return *reinterpret_cast<const bf16x8*>(p);
}
__device__ __forceinline__ void store4bf(__hip_bfloat16* p, f32x4 v) {
    union { __hip_bfloat16 h[4]; uint2 u; } t;
    #pragma unroll
    for (int r = 0; r < 4; ++r) t.h[r] = (__hip_bfloat16)v[r];
    *reinterpret_cast<uint2*>(p) = t.u;
}

// ---------------------------------------------------------------------------
// Kernel 0: weight prep. Wr[t][co][tap][ci] bf16 (t: q,k,v,i,f,g,o),
// Wa[t4][co][ci] bf16. grid 16640 x 256, one thread per element.
// ---------------------------------------------------------------------------
__global__ __launch_bounds__(256) void prep_kernel(
    const float* __restrict__ Wq, const float* __restrict__ Wk,
    const float* __restrict__ Wv, const float* __restrict__ Wix,
    const float* __restrict__ Wfx, const float* __restrict__ Wgx,
    const float* __restrict__ Wox, const float* __restrict__ Wia,
    const float* __restrict__ Wfa, const float* __restrict__ Wga,
    const float* __restrict__ Woa,
    __hip_bfloat16* __restrict__ Wr, __hip_bfloat16* __restrict__ Wa)
{
    const int i = blockIdx.x * 256 + threadIdx.x;
    const int N1 = 7 * WRT;
    if (i < N1) {
        const int t = i / WRT, r = i % WRT;
        const int co = r / 1152, r2 = r % 1152;
        const int tap = r2 / 128, ci = r2 % 128;
        const float* src;
        switch (t) {
            case 0: src = Wq;  break;  case 1: src = Wk;  break;
            case 2: src = Wv;  break;  case 3: src = Wix; break;
            case 4: src = Wfx; break;  case 5: src = Wgx; break;
            default: src = Wox;
        }
        Wr[i] = (__hip_bfloat16)src[(size_t)co * 1152 + ci * 9 + tap];
    } else {
        const int j = i - N1;               // < 4*32768
        const int t = j / 32768, r = j % 32768;
        const float* src = (t == 0) ? Wia : (t == 1) ? Wfa : (t == 2) ? Wga : Woa;
        Wa[j] = (__hip_bfloat16)src[r];
    }
}

// ---------------------------------------------------------------------------
// Kernel 1: proj -> xhT [ng][2304][128] bf16 (pixel-major, ch-contiguous).
// ch 0..63 = x = Wx*x_in + Wig*h (group g), ch 64..127 = h (group g).
// grid (144, 16), block 256. Block = one (ng, 16-pixel tile), all 128 ch.
// ---------------------------------------------------------------------------
__global__ __launch_bounds__(256) void proj_kernel(
    const float* __restrict__ x_in, const float* __restrict__ h,
    const float* __restrict__ W_x, const float* __restrict__ W_ig,
    __hip_bfloat16* __restrict__ xhT)
{
    const int pt = blockIdx.x;          // 0..143
    const int ng = blockIdx.y;          // 0..15
    const int n = ng >> 3, g = ng & 7;
    const int p0 = pt * 16;
    const int tid = threadIdx.x;
    const int pix = tid & 15, jj = tid >> 4;   // jj 0..15 -> 4 out-ch each

    __shared__ float xs[CIN * 16];
    __shared__ float hs[CC * 16];

    const float* xb = x_in + (size_t)n * CIN * PP;
    const float* hb = h + (size_t)n * CC * PP;
    #pragma unroll
    for (int k = 0; k < 16; ++k) {
        const int idx = k * 256 + tid;
        xs[idx] = xb[(size_t)(idx >> 4) * PP + p0 + (idx & 15)];
    }
    #pragma unroll
    for (int k = 0; k < 32; ++k) {
        const int idx = k * 256 + tid;
        hs[idx] = hb[(size_t)(idx >> 4) * PP + p0 + (idx & 15)];
    }
    __syncthreads();

    const int c0 = g * 64 + jj * 4;
    const float* w0 = W_x + (size_t)(c0 + 0) * CIN;
    const float* w1 = W_x + (size_t)(c0 + 1) * CIN;
    const float* w2 = W_x + (size_t)(c0 + 2) * CIN;
    const float* w3 = W_x + (size_t)(c0 + 3) * CIN;
    float a0 = 0.f, a1 = 0.f, a2 = 0.f, a3 = 0.f;
    #pragma unroll 4
    for (int ci = 0; ci < CIN; ++ci) {
        const float xv = xs[ci * 16 + pix];
        a0 += w0[ci] * xv; a1 += w1[ci] * xv;
        a2 += w2[ci] * xv; a3 += w3[ci] * xv;
    }
    const float* u0 = W_ig + (size_t)(c0 + 0) * CC;
    const float* u1 = W_ig + (size_t)(c0 + 1) * CC;
    const float* u2 = W_ig + (size_t)(c0 + 2) * CC;
    const float* u3 = W_ig + (size_t)(c0 + 3) * CC;
    #pragma unroll 4
    for (int ci = 0; ci < CC; ++ci) {
        const float hv = hs[ci * 16 + pix];
        a0 += u0[ci] * hv; a1 += u1[ci] * hv;
        a2 += u2[ci] * hv; a3 += u3[ci] * hv;
    }

    __hip_bfloat16* dst = xhT + ((size_t)ng * PP + p0 + pix) * 128;
    f32x4 xv4 = {a0, a1, a2, a3};
    store4bf(dst + jj * 4, xv4);
    f32x4 hv4 = {hs[(c0 + 0) * 16 + pix], hs[(c0 + 1) * 16 + pix],
                 hs[(c0 + 2) * 16 + pix], hs[(c0 + 3) * 16 + pix]};
    store4bf(dst + 64 + jj * 4, hv4);
}

// ---------------------------------------------------------------------------
// Kernel 2: fused q/k/v grouped 3x3 conv via MFMA implicit GEMM.
// Block = (tensor, ng, 4 output rows); 4 waves = 1 row each; M=64, N=48,
// K=1152 done in 2 channel-halves (LDS restage between halves).
// q -> qT [ng][2304][64]; k -> kT [ng][2116][64]; v -> v [ng][64][2120].
// grid 576 x 256. XCD-swizzled decode.
// ---------------------------------------------------------------------------
__global__ __launch_bounds__(256) void conv_qkv_kernel(
    const __hip_bfloat16* __restrict__ xhT, const __hip_bfloat16* __restrict__ Wr,
    __hip_bfloat16* __restrict__ qT, __hip_bfloat16* __restrict__ kT,
    __hip_bfloat16* __restrict__ v)
{
    const int b = blockIdx.x;
    const int xcd = b & 7;
    const int j = b >> 3;                 // 0..71
    const int s = xcd + 8 * (j / 12);     // 0..47 (tensor*16+ng)
    const int yt = j % 12;
    const int t = s / 16;                 // 0=q 1=k 2=v
    const int ng = s % 16;
    const int g = ng & 7;
    const int tid = threadIdx.x;
    const int w = tid >> 6, lane = tid & 63;
    const int col = lane & 15, quad = lane >> 4;
    const int y0 = yt * 4;
    const int yy = y0 + w;                // this wave's output row
    const int ohw = (t == 0) ? 48 : 46;
    const int d0 = (t == 0) ? -1 : 0;     // dy0 == dx0
    const bool wave_active = (yy < ohw);

    __shared__ __hip_bfloat16 st[8 * 288 * 8];   // [chunk][6*48 pix][8ch]

    const __hip_bfloat16* slab = xhT + (size_t)ng * PP * 128;
    const __hip_bfloat16* wbase =
        Wr + (size_t)t * WRT + ((size_t)(g * 64) + col) * 1152;

    f32x4 acc[12];
    #pragma unroll
    for (int i = 0; i < 12; ++i) acc[i] = (f32x4){0.f, 0.f, 0.f, 0.f};

    for (int hc = 0; hc < 2; ++hc) {
        __syncthreads();
        // stage 6 rows x 48 px x 64 ch(half): 2304 16B units
        #pragma unroll
        for (int it = 0; it < 9; ++it) {
            const int u = it * 256 + tid;
            const int lr = u / 384;
            const int rem = u % 384;
            const int px = rem >> 3, ck = rem & 7;
            int ry = y0 + d0 + lr;
            ry = max(0, min(47, ry));
            *reinterpret_cast<bf16x8*>(st + ((ck * 288) + lr * 48 + px) * 8) =
                ldb8(slab + ((size_t)(ry * 48 + px)) * 128 + hc * 64 + ck * 8);
        }
        __syncthreads();
        if (!wave_active) continue;

        for (int ky = 0; ky < 3; ++ky) {
            const int ry = yy + ky + d0;
            if (ry < 0 || ry > 47) continue;
            const int lr = w + ky;
            for (int kx = 0; kx < 3; ++kx) {
                const int tap = ky * 3 + kx;
                #pragma unroll
                for (int c32 = 0; c32 < 2; ++c32) {
                    bf16x8 bfr[3];
                    #pragma unroll
                    for (int nf = 0; nf < 3; ++nf) {
                        const int px = nf * 16 + col + kx + d0;
                        const int pxc = max(0, min(47, px));
                        bf16x8 tmp = *reinterpret_cast<const bf16x8*>(
                            st + (((c32 * 4 + quad) * 288) + lr * 48 + pxc) * 8);
                        bfr[nf] = (px == pxc) ? tmp : (bf16x8)(__bf16)0.f;
                    }
                    const __hip_bfloat16* wp =
                        wbase + tap * 128 + hc * 64 + c32 * 32 + quad * 8;
                    if (t != 2) {
                        #pragma unroll
                        for (int cf = 0; cf < 4; ++cf) {
                            const bf16x8 af = ldb8(wp + (size_t)(cf * 16) * 1152);
                            #pragma unroll
                            for (int nf = 0; nf < 3; ++nf)
                                acc[cf * 3 + nf] = __builtin_amdgcn_mfma_f32_16x16x32_bf16(
                                    af, bfr[nf], acc[cf * 3 + nf], 0, 0, 0);
                        }
                    } else {
                        #pragma unroll
                        for (int cf = 0; cf < 4; ++cf) {
                            const bf16x8 af = ldb8(wp + (size_t)(cf * 16) * 1152);
                            #pragma unroll
                            for (int nf = 0; nf < 3; ++nf)
                                acc[cf * 3 + nf] = __builtin_amdgcn_mfma_f32_16x16x32_bf16(
                                    bfr[nf], af, acc[cf * 3 + nf], 0, 0, 0);
                        }
                    }
                }
            }
        }
    }

    if (!wave_active) return;
    if (t == 0) {
        __hip_bfloat16* dst = qT + (size_t)ng * PP * 64;
        #pragma unroll
        for (int cf = 0; cf < 4; ++cf)
            #pragma unroll
            for (int nf = 0; nf < 3; ++nf) {
                const int pix = yy * 48 + nf * 16 + col;
                store4bf(dst + (size_t)pix * 64 + cf * 16 + quad * 4, acc[cf * 3 + nf]);
            }
    } else if (t == 1) {
        __hip_bfloat16* dst = kT + (size_t)ng * DD * 64;
        #pragma unroll
        for (int cf = 0; cf < 4; ++cf)
            #pragma unroll
            for (int nf = 0; nf < 3; ++nf) {
                const int x = nf * 16 + col;
                if (x < 46) {
                    const int pix = yy * 46 + x;
                    store4bf(dst + (size_t)pix * 64 + cf * 16 + quad * 4, acc[cf * 3 + nf]);
                }
            }
    } else {
        // v: C[m=pix][n=co] (operands were swapped)
        __hip_bfloat16* dst = v + (size_t)ng * 64 * DPADV;
        #pragma unroll
        for (int cf = 0; cf < 4; ++cf) {        // co frag
            const int co = cf * 16 + col;
            #pragma unroll
            for (int nf = 0; nf < 3; ++nf) {    // pix frag
                const int x4 = nf * 16 + quad * 4;
                #pragma unroll
                for (int r = 0; r < 4; ++r) {
                    if (x4 + r < 46)
                        dst[(size_t)co * DPADV + yy * 46 + x4 + r] =
                            (__hip_bfloat16)acc[cf * 3 + nf][r];
                }
            }
        }
    }
}

// ---------------------------------------------------------------------------
// Kernel 3: MFMA flash attention (unchanged from R3; correct & fast).
// qa: qT in / aT out (aliased); kT: [ng][2116][64]; v: [ng][64][2120].
// grid 576 x 256.
// ---------------------------------------------------------------------------
__global__ __launch_bounds__(256) void attn_kernel(
    __hip_bfloat16* qa,
    const __hip_bfloat16* __restrict__ kT,
    const __hip_bfloat16* __restrict__ vT,
    const float* __restrict__ tau)
{
    const int idx = blockIdx.x;
    const int j3  = idx >> 3;
    const int ng  = (idx & 7) + ((j3 >= 36) ? 8 : 0);
    const int qt  = j3 - ((j3 >= 36) ? 36 : 0);
    const int tid  = threadIdx.x;
    const int w    = tid >> 6;
    const int lane = tid & 63;
    const int col  = lane & 15;
    const int quad = lane >> 4;
    const int qbase = qt * 64 + w * 16;
    const float t = tau[ng & 7];

    __hip_bfloat16* qrow = qa + ((size_t)ng * PP + qbase + col) * CGR;
    const bf16x8 qf0 = ldb8(qrow + quad * 8);
    const bf16x8 qf1 = ldb8(qrow + 32 + quad * 8);

    const __hip_bfloat16* kbase = kT + (size_t)ng * DD * CGR;
    const __hip_bfloat16* vbase = vT + (size_t)ng * CGR * DPADV;

    f32x4 acc[4];
    #pragma unroll
    for (int cf = 0; cf < 4; ++cf) acc[cf] = (f32x4){0.f, 0.f, 0.f, 0.f};
    float m = -INFINITY, l = 0.f;
    const f32x4 zero = {0.f, 0.f, 0.f, 0.f};

    for (int dbase = 0; dbase < 2144; dbase += 32) {
        const int dr0 = min(dbase + col,      DD - 1);
        const int dr1 = min(dbase + 16 + col, DD - 1);
        const __hip_bfloat16* k0 = kbase + (size_t)dr0 * CGR + quad * 8;
        const __hip_bfloat16* k1 = kbase + (size_t)dr1 * CGR + quad * 8;
        f32x4 S0 = __builtin_amdgcn_mfma_f32_16x16x32_bf16(ldb8(k0), qf0, zero, 0, 0, 0);
        S0 = __builtin_amdgcn_mfma_f32_16x16x32_bf16(ldb8(k0 + 32), qf1, S0, 0, 0, 0);
        f32x4 S1 = __builtin_amdgcn_mfma_f32_16x16x32_bf16(ldb8(k1), qf0, zero, 0, 0, 0);
        S1 = __builtin_amdgcn_mfma_f32_16x16x32_bf16(ldb8(k1 + 32), qf1, S1, 0, 0, 0);

        float p0[4], p1[4];
        #pragma unroll
        for (int r = 0; r < 4; ++r) {
            const int d0v = dbase + quad * 4 + r;
            const int d1v = dbase + 16 + quad * 4 + r;
            p0[r] = (d0v < DD) ? S0[r] * t : -1e30f;
            p1[r] = (d1v < DD) ? S1[r] * t : -1e30f;
        }

        float smax = fmaxf(fmaxf(fmaxf(p0[0], p0[1]), fmaxf(p0[2], p0[3])),
                           fmaxf(fmaxf(p1[0], p1[1]), fmaxf(p1[2], p1[3])));
        smax = fmaxf(smax, __shfl_xor(smax, 16, 64));
        smax = fmaxf(smax, __shfl_xor(smax, 32, 64));
        const float mnew = fmaxf(m, smax);
        const float alpha = __expf(m - mnew);
        float lsum = 0.f;
        #pragma unroll
        for (int r = 0; r < 4; ++r) {
            p0[r] = __expf(p0[r] - mnew);
            p1[r] = __expf(p1[r] - mnew);
            lsum += p0[r] + p1[r];
        }
        lsum += __shfl_xor(lsum, 16, 64);
        lsum += __shfl_xor(lsum, 32, 64);
        l = l * alpha + lsum;
        m = mnew;
        #pragma unroll
        for (int cf = 0; cf < 4; ++cf)
            acc[cf] *= alpha;

        bf16x8 pt;
        #pragma unroll
        for (int jj = 0; jj < 8; ++jj) {
            const int srcLane = ((((quad & 1) * 2 + (jj >> 2)) << 4) | col);
            const float v0 = __shfl(p0[jj & 3], srcLane, 64);
            const float v1 = __shfl(p1[jj & 3], srcLane, 64);
            pt[jj] = (__bf16)((quad >= 2) ? v1 : v0);
        }

        const int dv = min(dbase + quad * 8, DD - 4);
        #pragma unroll
        for (int cf = 0; cf < 4; ++cf) {
            const __hip_bfloat16* vp = vbase + (size_t)(cf * 16 + col) * DPADV + dv;
            acc[cf] = __builtin_amdgcn_mfma_f32_16x16x32_bf16(ldb8(vp), pt, acc[cf], 0, 0, 0);
        }
    }

    const float inv = 1.f / l;
    __hip_bfloat16* arow = qa + ((size_t)ng * PP + qbase + col) * CGR;
    #pragma unroll
    for (int cf = 0; cf < 4; ++cf)
        #pragma unroll
        for (int r = 0; r < 4; ++r)
            arow[cf * 16 + quad * 4 + r] = (__hip_bfloat16)(acc[cf][r] * inv);
}

// ---------------------------------------------------------------------------
// Kernel 4: fused gates via MFMA + LSTM update.
// Block = (ng, output row); 4 waves = gates i,f,g,o; M=64 each, N=48,
// K=1152 (3x3 conv on xh) + 64 (1x1 on a). grid 768 x 256, XCD-swizzled.
// ---------------------------------------------------------------------------
__global__ __launch_bounds__(256) void gates_kernel(
    const __hip_bfloat16* __restrict__ xhT, const __hip_bfloat16* __restrict__ aT,
    const float* __restrict__ c_in,
    const __hip_bfloat16* __restrict__ Wr, const __hip_bfloat16* __restrict__ Wa,
    const float* __restrict__ b_i, const float* __restrict__ b_f,
    const float* __restrict__ b_g, const float* __restrict__ b_o,
    float* __restrict__ h_out)
{
    const int b = blockIdx.x;
    const int xcd = b & 7;
    const int j = b >> 3;                 // 0..95
    const int ng = xcd + 8 * (j / 48);
    const int yy = j % 48;
    const int n = ng >> 3, g = ng & 7;
    const int tid = threadIdx.x;
    const int w = tid >> 6, lane = tid & 63;
    const int col = lane & 15, quad = lane >> 4;

    __shared__ char smem[16 * 144 * 8 * 2];      // 36,864 B
    __hip_bfloat16* st = (__hip_bfloat16*)smem;  // [16 chunk][3*48 pix][8]
    float* ex = (float*)smem;                    // later: [4 gate][32 co][48 px]

    const __hip_bfloat16* slab = xhT + (size_t)ng * PP * 128;

    // stage 3 input rows (yy-1..yy+1, clamped), all 128 ch
    #pragma unroll
    for (int it = 0; it < 9; ++it) {
        const int u = it * 256 + tid;
        const int lr = u / 768;
        const int rem = u % 768;
        const int px = rem >> 4, ck = rem & 15;
        int ry = yy - 1 + lr;
        ry = max(0, min(47, ry));
        *reinterpret_cast<bf16x8*>(st + ((ck * 144) + lr * 48 + px) * 8) =
            ldb8(slab + ((size_t)(ry * 48 + px)) * 128 + ck * 8);
    }
    __syncthreads();

    f32x4 acc[12];
    #pragma unroll
    for (int i = 0; i < 12; ++i) acc[i] = (f32x4){0.f, 0.f, 0.f, 0.f};

    const __hip_bfloat16* wbase =
        Wr + (size_t)(3 + w) * WRT + ((size_t)(g * 64) + col) * 1152;

    for (int ky = 0; ky < 3; ++ky) {
        const int ry = yy + ky - 1;
        if (ry < 0 || ry > 47) continue;
        const int lr = ky;
        for (int kx = 0; kx < 3; ++kx) {
            const int tap = ky * 3 + kx;
            #pragma unroll
            for (int c32 = 0; c32 < 4; ++c32) {
                bf16x8 bfr[3];
                #pragma unroll
                for (int nf = 0; nf < 3; ++nf) {
                    const int px = nf * 16 + col + kx - 1;
                    const int pxc = max(0, min(47, px));
                    bf16x8 tmp = *reinterpret_cast<const bf16x8*>(
                        st + (((c32 * 4 + quad) * 144) + lr * 48 + pxc) * 8);
                    bfr[nf] = (px == pxc) ? tmp : (bf16x8)(__bf16)0.f;
                }
                const __hip_bfloat16* wp = wbase + tap * 128 + c32 * 32 + quad * 8;
                #pragma unroll
                for (int cf = 0; cf < 4; ++cf) {
                    const bf16x8 af = ldb8(wp + (size_t)(cf * 16) * 1152);
                    #pragma unroll
                    for (int nf = 0; nf < 3; ++nf)
                        acc[cf * 3 + nf] = __builtin_amdgcn_mfma_f32_16x16x32_bf16(
                            af, bfr[nf], acc[cf * 3 + nf], 0, 0, 0);
                }
            }
        }
    }

    // 1x1 on a (K=64)
    {
        const __hip_bfloat16* wa =
            Wa + (size_t)w * 32768 + ((size_t)(g * 64) + col) * 64;
        const __hip_bfloat16* ab = aT + ((size_t)ng * PP + yy * 48) * 64;
        #pragma unroll
        for (int c32 = 0; c32 < 2; ++c32) {
            bf16x8 bfr[3];
            #pragma unroll
            for (int nf = 0; nf < 3; ++nf)
                bfr[nf] = ldb8(ab + (size_t)(nf * 16 + col) * 64 + c32 * 32 + quad * 8);
            #pragma unroll
            for (int cf = 0; cf < 4; ++cf) {
                const bf16x8 af = ldb8(wa + (size_t)(cf * 16) * 64 + c32 * 32 + quad * 8);
                #pragma unroll
                for (int nf = 0; nf < 3; ++nf)
                    acc[cf * 3 + nf] = __builtin_amdgcn_mfma_f32_16x16x32_bf16(
                        af, bfr[nf], acc[cf * 3 + nf], 0, 0, 0);
            }
        }
    }

    // bias
    const float* bias = (w == 0) ? b_i : (w == 1) ? b_f : (w == 2) ? b_g : b_o;
    #pragma unroll
    for (int cf = 0; cf < 4; ++cf) {
        #pragma unroll
        for (int r = 0; r < 4; ++r) {
            const float bv = bias[g * 64 + cf * 16 + quad * 4 + r];
            #pragma unroll
            for (int nf = 0; nf < 3; ++nf)
                acc[cf * 3 + nf][r] += bv;
        }
    }

    // exchange + LSTM, two co-halves of 32
    for (int hh = 0; hh < 2; ++hh) {
        __syncthreads();
        #pragma unroll
        for (int cc = 0; cc < 2; ++cc) {
            const int cf = 2 * hh + cc;
            #pragma unroll
            for (int nf = 0; nf < 3; ++nf)
                #pragma unroll
                for (int r = 0; r < 4; ++r)
                    ex[(size_t)w * 1536 + (cc * 16 + quad * 4 + r) * 48 + nf * 16 + col] =
                        acc[cf * 3 + nf][r];
        }
        __syncthreads();
        #pragma unroll
        for (int k2 = 0; k2 < 6; ++k2) {
            const int idx = k2 * 256 + tid;      // 0..1535
            const int co32 = idx / 48, px = idx % 48;
            const float iv = ex[0 * 1536 + co32 * 48 + px];
            const float fv = ex[1 * 1536 + co32 * 48 + px];
            const float gv = ex[2 * 1536 + co32 * 48 + px];
            const float ov = ex[3 * 1536 + co32 * 48 + px];
            const int c = g * 64 + hh * 32 + co32;
            const size_t off = ((size_t)n * CC + c) * PP + yy * 48 + px;
            const float ig = 1.f / (1.f + __expf(-iv));
            const float fg = 1.f / (1.f + __expf(-fv));
            const float gg = tanhf(gv);
            const float og = 1.f / (1.f + __expf(-ov));
            const float cn = fg * c_in[off] + ig * gg;
            h_out[off] = og * tanhf(cn);
        }
    }
}

// ---------------------------------------------------------------------------
extern "C" void kernel_launch(void* const* d_in, const int* in_sizes, int n_in,
                              void* d_out, int out_size, void* d_ws, size_t ws_size,
                              hipStream_t stream)
{
    const float* x_in = (const float*)d_in[0];
    const float* h    = (const float*)d_in[1];
    const float* c    = (const float*)d_in[2];
    const float* tau  = (const float*)d_in[3];
    const float* W_x  = (const float*)d_in[4];
    const float* W_ig = (const float*)d_in[5];
    const float* W_q  = (const float*)d_in[6];
    const float* W_k  = (const float*)d_in[7];
    const float* W_v  = (const float*)d_in[8];
    const float* Wi_a = (const float*)d_in[9];
    const float* Wi_x = (const float*)d_in[10];
    const float* b_i  = (const float*)d_in[11];
    const float* Wf_a = (const float*)d_in[12];
    const float* Wf_x = (const float*)d_in[13];
    const float* b_f  = (const float*)d_in[14];
    const float* Wg_a = (const float*)d_in[15];
    const float* Wg_x = (const float*)d_in[16];
    const float* b_g  = (const float*)d_in[17];
    const float* Wo_a = (const float*)d_in[18];
    const float* Wo_x = (const float*)d_in[19];
    const float* b_o  = (const float*)d_in[20];
    float* out = (float*)d_out;

    // Workspace (bf16 elements), total 31,350,784 B (~29.9 MB)
    __hip_bfloat16* wsb = (__hip_bfloat16*)d_ws;
    __hip_bfloat16* xhT = wsb;                        // 16*2304*128 = 4,718,592
    __hip_bfloat16* qa  = xhT + (size_t)4718592;      // 16*2304*64  = 2,359,296
    __hip_bfloat16* kT  = qa  + (size_t)2359296;      // 16*2116*64  = 2,166,784
    __hip_bfloat16* vv  = kT  + (size_t)2166784;      // 16*64*2120  = 2,170,880
    __hip_bfloat16* Wr  = vv  + (size_t)2170880;      // 7*589824    = 4,128,768
    __hip_bfloat16* Wa  = Wr  + (size_t)4128768;      // 4*32768     =   131,072

    dim3 blk(256);
    prep_kernel<<<dim3(16640), blk, 0, stream>>>(
        W_q, W_k, W_v, Wi_x, Wf_x, Wg_x, Wo_x, Wi_a, Wf_a, Wg_a, Wo_a, Wr, Wa);
    proj_kernel<<<dim3(144, 16), blk, 0, stream>>>(x_in, h, W_x, W_ig, xhT);
    conv_qkv_kernel<<<dim3(576), blk, 0, stream>>>(xhT, Wr, qa, kT, vv);
    attn_kernel<<<dim3(576), blk, 0, stream>>>(qa, kT, vv, tau);
    gates_kernel<<<dim3(768), blk, 0, stream>>>(
        xhT, qa, c, Wr, Wa, b_i, b_f, b_g, b_o, out);
}

// Round 5
// 404.009 us; speedup vs baseline: 15.0989x; 1.4158x over previous
//
#include <hip/hip_runtime.h>
#include <hip/hip_bf16.h>
#include <math.h>

// Problem constants
#define NB   2
#define CIN  256
#define CC   512
#define GG   8
#define CGR  64
#define HH   48
#define WW   48
#define PP   (HH*WW)        // 2304
#define HD   46
#define WD   46
#define DD   (HD*WD)        // 2116
#define DPADV 2120          // v row stride (16B-aligned rows)
#define WRT  589824         // 512*9*128, per-tensor reordered weight stride

typedef __bf16 bf16x8 __attribute__((ext_vector_type(8)));
typedef float  f32x4  __attribute__((ext_vector_type(4)));

__device__ __forceinline__ bf16x8 ldb8(const __hip_bfloat16* p) {
    return *reinterpret_cast<const bf16x8*>(p);
}
__device__ __forceinline__ void store4bf(__hip_bfloat16* p, f32x4 v) {
    union { __hip_bfloat16 h[4]; uint2 u; } t;
    #pragma unroll
    for (int r = 0; r < 4; ++r) t.h[r] = (__hip_bfloat16)v[r];
    *reinterpret_cast<uint2*>(p) = t.u;
}

// ---------------------------------------------------------------------------
// Kernel 0: weight prep.
// Wr[t][co][tap][ci] bf16 (t: q,k,v,i,f,g,o)    7*589824
// Wa[t4][co][ci] bf16                            4*32768
// Wp[c][768] bf16 (256 W_x | 512 W_ig)           393216
// grid 18176 x 256, one thread per element.
// ---------------------------------------------------------------------------
__global__ __launch_bounds__(256) void prep_kernel(
    const float* __restrict__ Wq, const float* __restrict__ Wk,
    const float* __restrict__ Wv, const float* __restrict__ Wix,
    const float* __restrict__ Wfx, const float* __restrict__ Wgx,
    const float* __restrict__ Wox, const float* __restrict__ Wia,
    const float* __restrict__ Wfa, const float* __restrict__ Wga,
    const float* __restrict__ Woa, const float* __restrict__ Wx,
    const float* __restrict__ Wig,
    __hip_bfloat16* __restrict__ Wr, __hip_bfloat16* __restrict__ Wa,
    __hip_bfloat16* __restrict__ Wp)
{
    const int i = blockIdx.x * 256 + threadIdx.x;
    const int N1 = 7 * WRT;
    const int N2 = N1 + 4 * 32768;
    if (i < N1) {
        const int t = i / WRT, r = i % WRT;
        const int co = r / 1152, r2 = r % 1152;
        const int tap = r2 / 128, ci = r2 % 128;
        const float* src;
        switch (t) {
            case 0: src = Wq;  break;  case 1: src = Wk;  break;
            case 2: src = Wv;  break;  case 3: src = Wix; break;
            case 4: src = Wfx; break;  case 5: src = Wgx; break;
            default: src = Wox;
        }
        Wr[i] = (__hip_bfloat16)src[(size_t)co * 1152 + ci * 9 + tap];
    } else if (i < N2) {
        const int j = i - N1;
        const int t = j / 32768, r = j % 32768;
        const float* src = (t == 0) ? Wia : (t == 1) ? Wfa : (t == 2) ? Wga : Woa;
        Wa[j] = (__hip_bfloat16)src[r];
    } else {
        const int j = i - N2;               // < 393216
        const int c = j / 768, k = j % 768;
        Wp[j] = (__hip_bfloat16)((k < 256) ? Wx[(size_t)c * 256 + k]
                                           : Wig[(size_t)c * 512 + (k - 256)]);
    }
}

// ---------------------------------------------------------------------------
// Kernel 1a: transpose/convert. x_in -> xiT [n][2304][256] bf16;
// h -> xhT [ng][2304][128] channels 64..127 (h pass-through half).
// grid (144, 2), block 256. LDS tiles padded to stride 17 (<=2-way conflicts).
// ---------------------------------------------------------------------------
__global__ __launch_bounds__(256) void xpose_kernel(
    const float* __restrict__ x_in, const float* __restrict__ h,
    __hip_bfloat16* __restrict__ xiT, __hip_bfloat16* __restrict__ xhT)
{
    const int pt = blockIdx.x;          // 0..143
    const int n  = blockIdx.y;
    const int p0 = pt * 16;
    const int tid = threadIdx.x;

    __shared__ float xs[CIN * 17];
    __shared__ float hs[CC * 17];

    const float* xb = x_in + (size_t)n * CIN * PP;
    const float* hb = h + (size_t)n * CC * PP;
    #pragma unroll
    for (int k = 0; k < 16; ++k) {
        const int idx = k * 256 + tid;
        xs[(idx >> 4) * 17 + (idx & 15)] = xb[(size_t)(idx >> 4) * PP + p0 + (idx & 15)];
    }
    #pragma unroll
    for (int k = 0; k < 32; ++k) {
        const int idx = k * 256 + tid;
        hs[(idx >> 4) * 17 + (idx & 15)] = hb[(size_t)(idx >> 4) * PP + p0 + (idx & 15)];
    }
    __syncthreads();

    // xiT: 16 px * 32 chunks of 8 ch
    #pragma unroll
    for (int it = 0; it < 2; ++it) {
        const int u = it * 256 + tid;
        const int pix = u & 15, ck = u >> 4;
        union { __hip_bfloat16 h8[8]; bf16x8 v; } t;
        #pragma unroll
        for (int j = 0; j < 8; ++j)
            t.h8[j] = (__hip_bfloat16)xs[(ck * 8 + j) * 17 + pix];
        *reinterpret_cast<bf16x8*>(
            xiT + ((size_t)n * PP + p0 + pix) * 256 + ck * 8) = t.v;
    }
    // xhT h-half: 16 px * 64 chunks of 8 ch
    #pragma unroll
    for (int it = 0; it < 4; ++it) {
        const int u = it * 256 + tid;
        const int pix = u & 15, ck = u >> 4;     // ck 0..63
        const int g = ck >> 3, c8 = (ck & 7) * 8;
        union { __hip_bfloat16 h8[8]; bf16x8 v; } t;
        #pragma unroll
        for (int j = 0; j < 8; ++j)
            t.h8[j] = (__hip_bfloat16)hs[(ck * 8 + j) * 17 + pix];
        *reinterpret_cast<bf16x8*>(
            xhT + ((size_t)(n * GG + g) * PP + p0 + pix) * 128 + 64 + c8) = t.v;
    }
}

// ---------------------------------------------------------------------------
// Kernel 1b: proj GEMM via MFMA. Writes xhT x-half (ch 0..63).
// Wave = one output row: M=64 (group out-ch), N=48 px, K=768 (256 x + 512 h).
// B from xiT (x part) and xhT h-half (h part, already ch-contiguous/group).
// grid 192 x 256 (XCD-swizzled: b&7 = g).
// ---------------------------------------------------------------------------
__global__ __launch_bounds__(256) void proj_mfma_kernel(
    const __hip_bfloat16* __restrict__ xiT, const __hip_bfloat16* __restrict__ Wp,
    __hip_bfloat16* xhT)
{
    const int b = blockIdx.x;
    const int g = b & 7;
    const int j = b >> 3;                // 0..23
    const int n = j / 12;
    const int yt = j % 12;
    const int ng = n * GG + g;
    const int tid = threadIdx.x;
    const int w = tid >> 6, lane = tid & 63;
    const int col = lane & 15, quad = lane >> 4;
    const int y = yt * 4 + w;

    f32x4 acc[12];
    #pragma unroll
    for (int i = 0; i < 12; ++i) acc[i] = (f32x4){0.f, 0.f, 0.f, 0.f};

    const __hip_bfloat16* wbase = Wp + ((size_t)(g * 64) + col) * 768;

    for (int kk = 0; kk < 24; ++kk) {
        bf16x8 bfr[3];
        if (kk < 8) {
            const __hip_bfloat16* bp =
                xiT + ((size_t)n * PP + y * 48 + col) * 256 + kk * 32 + quad * 8;
            #pragma unroll
            for (int nf = 0; nf < 3; ++nf)
                bfr[nf] = ldb8(bp + (size_t)(nf * 16) * 256);
        } else {
            const int kh = kk - 8;
            const int gp = kh >> 1;
            const int c0 = (kh & 1) * 32;
            const __hip_bfloat16* bp =
                xhT + ((size_t)(n * GG + gp) * PP + y * 48 + col) * 128 + 64 + c0 + quad * 8;
            #pragma unroll
            for (int nf = 0; nf < 3; ++nf)
                bfr[nf] = ldb8(bp + (size_t)(nf * 16) * 128);
        }
        const __hip_bfloat16* wp = wbase + kk * 32 + quad * 8;
        #pragma unroll
        for (int cf = 0; cf < 4; ++cf) {
            const bf16x8 af = ldb8(wp + (size_t)(cf * 16) * 768);
            #pragma unroll
            for (int nf = 0; nf < 3; ++nf)
                acc[cf * 3 + nf] = __builtin_amdgcn_mfma_f32_16x16x32_bf16(
                    af, bfr[nf], acc[cf * 3 + nf], 0, 0, 0);
        }
    }

    __hip_bfloat16* dst = xhT + (size_t)ng * PP * 128;
    #pragma unroll
    for (int cf = 0; cf < 4; ++cf)
        #pragma unroll
        for (int nf = 0; nf < 3; ++nf) {
            const int pix = y * 48 + nf * 16 + col;
            store4bf(dst + (size_t)pix * 128 + cf * 16 + quad * 4, acc[cf * 3 + nf]);
        }
}

// ---------------------------------------------------------------------------
// Kernel 2: fused q/k/v grouped 3x3 conv via MFMA implicit GEMM.
// grid 576 x 256. XCD-swizzled decode. (unchanged from R4)
// ---------------------------------------------------------------------------
__global__ __launch_bounds__(256) void conv_qkv_kernel(
    const __hip_bfloat16* __restrict__ xhT, const __hip_bfloat16* __restrict__ Wr,
    __hip_bfloat16* __restrict__ qT, __hip_bfloat16* __restrict__ kT,
    __hip_bfloat16* __restrict__ v)
{
    const int b = blockIdx.x;
    const int xcd = b & 7;
    const int j = b >> 3;
    const int s = xcd + 8 * (j / 12);
    const int yt = j % 12;
    const int t = s / 16;
    const int ng = s % 16;
    const int g = ng & 7;
    const int tid = threadIdx.x;
    const int w = tid >> 6, lane = tid & 63;
    const int col = lane & 15, quad = lane >> 4;
    const int y0 = yt * 4;
    const int yy = y0 + w;
    const int ohw = (t == 0) ? 48 : 46;
    const int d0 = (t == 0) ? -1 : 0;
    const bool wave_active = (yy < ohw);

    __shared__ __hip_bfloat16 st[8 * 288 * 8];

    const __hip_bfloat16* slab = xhT + (size_t)ng * PP * 128;
    const __hip_bfloat16* wbase =
        Wr + (size_t)t * WRT + ((size_t)(g * 64) + col) * 1152;

    f32x4 acc[12];
    #pragma unroll
    for (int i = 0; i < 12; ++i) acc[i] = (f32x4){0.f, 0.f, 0.f, 0.f};

    for (int hc = 0; hc < 2; ++hc) {
        __syncthreads();
        #pragma unroll
        for (int it = 0; it < 9; ++it) {
            const int u = it * 256 + tid;
            const int lr = u / 384;
            const int rem = u % 384;
            const int px = rem >> 3, ck = rem & 7;
            int ry = y0 + d0 + lr;
            ry = max(0, min(47, ry));
            *reinterpret_cast<bf16x8*>(st + ((ck * 288) + lr * 48 + px) * 8) =
                ldb8(slab + ((size_t)(ry * 48 + px)) * 128 + hc * 64 + ck * 8);
        }
        __syncthreads();
        if (!wave_active) continue;

        for (int ky = 0; ky < 3; ++ky) {
            const int ry = yy + ky + d0;
            if (ry < 0 || ry > 47) continue;
            const int lr = w + ky;
            for (int kx = 0; kx < 3; ++kx) {
                const int tap = ky * 3 + kx;
                #pragma unroll
                for (int c32 = 0; c32 < 2; ++c32) {
                    bf16x8 bfr[3];
                    #pragma unroll
                    for (int nf = 0; nf < 3; ++nf) {
                        const int px = nf * 16 + col + kx + d0;
                        const int pxc = max(0, min(47, px));
                        bf16x8 tmp = *reinterpret_cast<const bf16x8*>(
                            st + (((c32 * 4 + quad) * 288) + lr * 48 + pxc) * 8);
                        bfr[nf] = (px == pxc) ? tmp : (bf16x8)(__bf16)0.f;
                    }
                    const __hip_bfloat16* wp =
                        wbase + tap * 128 + hc * 64 + c32 * 32 + quad * 8;
                    if (t != 2) {
                        #pragma unroll
                        for (int cf = 0; cf < 4; ++cf) {
                            const bf16x8 af = ldb8(wp + (size_t)(cf * 16) * 1152);
                            #pragma unroll
                            for (int nf = 0; nf < 3; ++nf)
                                acc[cf * 3 + nf] = __builtin_amdgcn_mfma_f32_16x16x32_bf16(
                                    af, bfr[nf], acc[cf * 3 + nf], 0, 0, 0);
                        }
                    } else {
                        #pragma unroll
                        for (int cf = 0; cf < 4; ++cf) {
                            const bf16x8 af = ldb8(wp + (size_t)(cf * 16) * 1152);
                            #pragma unroll
                            for (int nf = 0; nf < 3; ++nf)
                                acc[cf * 3 + nf] = __builtin_amdgcn_mfma_f32_16x16x32_bf16(
                                    bfr[nf], af, acc[cf * 3 + nf], 0, 0, 0);
                        }
                    }
                }
            }
        }
    }

    if (!wave_active) return;
    if (t == 0) {
        __hip_bfloat16* dst = qT + (size_t)ng * PP * 64;
        #pragma unroll
        for (int cf = 0; cf < 4; ++cf)
            #pragma unroll
            for (int nf = 0; nf < 3; ++nf) {
                const int pix = yy * 48 + nf * 16 + col;
                store4bf(dst + (size_t)pix * 64 + cf * 16 + quad * 4, acc[cf * 3 + nf]);
            }
    } else if (t == 1) {
        __hip_bfloat16* dst = kT + (size_t)ng * DD * 64;
        #pragma unroll
        for (int cf = 0; cf < 4; ++cf)
            #pragma unroll
            for (int nf = 0; nf < 3; ++nf) {
                const int x = nf * 16 + col;
                if (x < 46) {
                    const int pix = yy * 46 + x;
                    store4bf(dst + (size_t)pix * 64 + cf * 16 + quad * 4, acc[cf * 3 + nf]);
                }
            }
    } else {
        __hip_bfloat16* dst = v + (size_t)ng * 64 * DPADV;
        #pragma unroll
        for (int cf = 0; cf < 4; ++cf) {
            const int co = cf * 16 + col;
            #pragma unroll
            for (int nf = 0; nf < 3; ++nf) {
                const int x4 = nf * 16 + quad * 4;
                #pragma unroll
                for (int r = 0; r < 4; ++r) {
                    if (x4 + r < 46)
                        dst[(size_t)co * DPADV + yy * 46 + x4 + r] =
                            (__hip_bfloat16)acc[cf * 3 + nf][r];
                }
            }
        }
    }
}

// ---------------------------------------------------------------------------
// Kernel 3: MFMA flash attention (unchanged). grid 576 x 256.
// ---------------------------------------------------------------------------
__global__ __launch_bounds__(256) void attn_kernel(
    __hip_bfloat16* qa,
    const __hip_bfloat16* __restrict__ kT,
    const __hip_bfloat16* __restrict__ vT,
    const float* __restrict__ tau)
{
    const int idx = blockIdx.x;
    const int j3  = idx >> 3;
    const int ng  = (idx & 7) + ((j3 >= 36) ? 8 : 0);
    const int qt  = j3 - ((j3 >= 36) ? 36 : 0);
    const int tid  = threadIdx.x;
    const int w    = tid >> 6;
    const int lane = tid & 63;
    const int col  = lane & 15;
    const int quad = lane >> 4;
    const int qbase = qt * 64 + w * 16;
    const float t = tau[ng & 7];

    __hip_bfloat16* qrow = qa + ((size_t)ng * PP + qbase + col) * CGR;
    const bf16x8 qf0 = ldb8(qrow + quad * 8);
    const bf16x8 qf1 = ldb8(qrow + 32 + quad * 8);

    const __hip_bfloat16* kbase = kT + (size_t)ng * DD * CGR;
    const __hip_bfloat16* vbase = vT + (size_t)ng * CGR * DPADV;

    f32x4 acc[4];
    #pragma unroll
    for (int cf = 0; cf < 4; ++cf) acc[cf] = (f32x4){0.f, 0.f, 0.f, 0.f};
    float m = -INFINITY, l = 0.f;
    const f32x4 zero = {0.f, 0.f, 0.f, 0.f};

    for (int dbase = 0; dbase < 2144; dbase += 32) {
        const int dr0 = min(dbase + col,      DD - 1);
        const int dr1 = min(dbase + 16 + col, DD - 1);
        const __hip_bfloat16* k0 = kbase + (size_t)dr0 * CGR + quad * 8;
        const __hip_bfloat16* k1 = kbase + (size_t)dr1 * CGR + quad * 8;
        f32x4 S0 = __builtin_amdgcn_mfma_f32_16x16x32_bf16(ldb8(k0), qf0, zero, 0, 0, 0);
        S0 = __builtin_amdgcn_mfma_f32_16x16x32_bf16(ldb8(k0 + 32), qf1, S0, 0, 0, 0);
        f32x4 S1 = __builtin_amdgcn_mfma_f32_16x16x32_bf16(ldb8(k1), qf0, zero, 0, 0, 0);
        S1 = __builtin_amdgcn_mfma_f32_16x16x32_bf16(ldb8(k1 + 32), qf1, S1, 0, 0, 0);

        float p0[4], p1[4];
        #pragma unroll
        for (int r = 0; r < 4; ++r) {
            const int d0v = dbase + quad * 4 + r;
            const int d1v = dbase + 16 + quad * 4 + r;
            p0[r] = (d0v < DD) ? S0[r] * t : -1e30f;
            p1[r] = (d1v < DD) ? S1[r] * t : -1e30f;
        }

        float smax = fmaxf(fmaxf(fmaxf(p0[0], p0[1]), fmaxf(p0[2], p0[3])),
                           fmaxf(fmaxf(p1[0], p1[1]), fmaxf(p1[2], p1[3])));
        smax = fmaxf(smax, __shfl_xor(smax, 16, 64));
        smax = fmaxf(smax, __shfl_xor(smax, 32, 64));
        const float mnew = fmaxf(m, smax);
        const float alpha = __expf(m - mnew);
        float lsum = 0.f;
        #pragma unroll
        for (int r = 0; r < 4; ++r) {
            p0[r] = __expf(p0[r] - mnew);
            p1[r] = __expf(p1[r] - mnew);
            lsum += p0[r] + p1[r];
        }
        lsum += __shfl_xor(lsum, 16, 64);
        lsum += __shfl_xor(lsum, 32, 64);
        l = l * alpha + lsum;
        m = mnew;
        #pragma unroll
        for (int cf = 0; cf < 4; ++cf)
            acc[cf] *= alpha;

        bf16x8 pt;
        #pragma unroll
        for (int jj = 0; jj < 8; ++jj) {
            const int srcLane = ((((quad & 1) * 2 + (jj >> 2)) << 4) | col);
            const float v0 = __shfl(p0[jj & 3], srcLane, 64);
            const float v1 = __shfl(p1[jj & 3], srcLane, 64);
            pt[jj] = (__bf16)((quad >= 2) ? v1 : v0);
        }

        const int dv = min(dbase + quad * 8, DD - 4);
        #pragma unroll
        for (int cf = 0; cf < 4; ++cf) {
            const __hip_bfloat16* vp = vbase + (size_t)(cf * 16 + col) * DPADV + dv;
            acc[cf] = __builtin_amdgcn_mfma_f32_16x16x32_bf16(ldb8(vp), pt, acc[cf], 0, 0, 0);
        }
    }

    const float inv = 1.f / l;
    __hip_bfloat16* arow = qa + ((size_t)ng * PP + qbase + col) * CGR;
    #pragma unroll
    for (int cf = 0; cf < 4; ++cf)
        #pragma unroll
        for (int r = 0; r < 4; ++r)
            arow[cf * 16 + quad * 4 + r] = (__hip_bfloat16)(acc[cf][r] * inv);
}

// ---------------------------------------------------------------------------
// Kernel 4: fused gates via MFMA + LSTM update (unchanged). grid 768 x 256.
// ---------------------------------------------------------------------------
__global__ __launch_bounds__(256) void gates_kernel(
    const __hip_bfloat16* __restrict__ xhT, const __hip_bfloat16* __restrict__ aT,
    const float* __restrict__ c_in,
    const __hip_bfloat16* __restrict__ Wr, const __hip_bfloat16* __restrict__ Wa,
    const float* __restrict__ b_i, const float* __restrict__ b_f,
    const float* __restrict__ b_g, const float* __restrict__ b_o,
    float* __restrict__ h_out)
{
    const int b = blockIdx.x;
    const int xcd = b & 7;
    const int j = b >> 3;
    const int ng = xcd + 8 * (j / 48);
    const int yy = j % 48;
    const int n = ng >> 3, g = ng & 7;
    const int tid = threadIdx.x;
    const int w = tid >> 6, lane = tid & 63;
    const int col = lane & 15, quad = lane >> 4;

    __shared__ char smem[16 * 144 * 8 * 2];
    __hip_bfloat16* st = (__hip_bfloat16*)smem;
    float* ex = (float*)smem;

    const __hip_bfloat16* slab = xhT + (size_t)ng * PP * 128;

    #pragma unroll
    for (int it = 0; it < 9; ++it) {
        const int u = it * 256 + tid;
        const int lr = u / 768;
        const int rem = u % 768;
        const int px = rem >> 4, ck = rem & 15;
        int ry = yy - 1 + lr;
        ry = max(0, min(47, ry));
        *reinterpret_cast<bf16x8*>(st + ((ck * 144) + lr * 48 + px) * 8) =
            ldb8(slab + ((size_t)(ry * 48 + px)) * 128 + ck * 8);
    }
    __syncthreads();

    f32x4 acc[12];
    #pragma unroll
    for (int i = 0; i < 12; ++i) acc[i] = (f32x4){0.f, 0.f, 0.f, 0.f};

    const __hip_bfloat16* wbase =
        Wr + (size_t)(3 + w) * WRT + ((size_t)(g * 64) + col) * 1152;

    for (int ky = 0; ky < 3; ++ky) {
        const int ry = yy + ky - 1;
        if (ry < 0 || ry > 47) continue;
        const int lr = ky;
        for (int kx = 0; kx < 3; ++kx) {
            const int tap = ky * 3 + kx;
            #pragma unroll
            for (int c32 = 0; c32 < 4; ++c32) {
                bf16x8 bfr[3];
                #pragma unroll
                for (int nf = 0; nf < 3; ++nf) {
                    const int px = nf * 16 + col + kx - 1;
                    const int pxc = max(0, min(47, px));
                    bf16x8 tmp = *reinterpret_cast<const bf16x8*>(
                        st + (((c32 * 4 + quad) * 144) + lr * 48 + pxc) * 8);
                    bfr[nf] = (px == pxc) ? tmp : (bf16x8)(__bf16)0.f;
                }
                const __hip_bfloat16* wp = wbase + tap * 128 + c32 * 32 + quad * 8;
                #pragma unroll
                for (int cf = 0; cf < 4; ++cf) {
                    const bf16x8 af = ldb8(wp + (size_t)(cf * 16) * 1152);
                    #pragma unroll
                    for (int nf = 0; nf < 3; ++nf)
                        acc[cf * 3 + nf] = __builtin_amdgcn_mfma_f32_16x16x32_bf16(
                            af, bfr[nf], acc[cf * 3 + nf], 0, 0, 0);
                }
            }
        }
    }

    {
        const __hip_bfloat16* wa =
            Wa + (size_t)w * 32768 + ((size_t)(g * 64) + col) * 64;
        const __hip_bfloat16* ab = aT + ((size_t)ng * PP + yy * 48) * 64;
        #pragma unroll
        for (int c32 = 0; c32 < 2; ++c32) {
            bf16x8 bfr[3];
            #pragma unroll
            for (int nf = 0; nf < 3; ++nf)
                bfr[nf] = ldb8(ab + (size_t)(nf * 16 + col) * 64 + c32 * 32 + quad * 8);
            #pragma unroll
            for (int cf = 0; cf < 4; ++cf) {
                const bf16x8 af = ldb8(wa + (size_t)(cf * 16) * 64 + c32 * 32 + quad * 8);
                #pragma unroll
                for (int nf = 0; nf < 3; ++nf)
                    acc[cf * 3 + nf] = __builtin_amdgcn_mfma_f32_16x16x32_bf16(
                        af, bfr[nf], acc[cf * 3 + nf], 0, 0, 0);
            }
        }
    }

    const float* bias = (w == 0) ? b_i : (w == 1) ? b_f : (w == 2) ? b_g : b_o;
    #pragma unroll
    for (int cf = 0; cf < 4; ++cf) {
        #pragma unroll
        for (int r = 0; r < 4; ++r) {
            const float bv = bias[g * 64 + cf * 16 + quad * 4 + r];
            #pragma unroll
            for (int nf = 0; nf < 3; ++nf)
                acc[cf * 3 + nf][r] += bv;
        }
    }

    for (int hh = 0; hh < 2; ++hh) {
        __syncthreads();
        #pragma unroll
        for (int cc = 0; cc < 2; ++cc) {
            const int cf = 2 * hh + cc;
            #pragma unroll
            for (int nf = 0; nf < 3; ++nf)
                #pragma unroll
                for (int r = 0; r < 4; ++r)
                    ex[(size_t)w * 1536 + (cc * 16 + quad * 4 + r) * 48 + nf * 16 + col] =
                        acc[cf * 3 + nf][r];
        }
        __syncthreads();
        #pragma unroll
        for (int k2 = 0; k2 < 6; ++k2) {
            const int idx = k2 * 256 + tid;
            const int co32 = idx / 48, px = idx % 48;
            const float iv = ex[0 * 1536 + co32 * 48 + px];
            const float fv = ex[1 * 1536 + co32 * 48 + px];
            const float gv = ex[2 * 1536 + co32 * 48 + px];
            const float ov = ex[3 * 1536 + co32 * 48 + px];
            const int c = g * 64 + hh * 32 + co32;
            const size_t off = ((size_t)n * CC + c) * PP + yy * 48 + px;
            const float ig = 1.f / (1.f + __expf(-iv));
            const float fg = 1.f / (1.f + __expf(-fv));
            const float gg = tanhf(gv);
            const float og = 1.f / (1.f + __expf(-ov));
            const float cn = fg * c_in[off] + ig * gg;
            h_out[off] = og * tanhf(cn);
        }
    }
}

// ---------------------------------------------------------------------------
extern "C" void kernel_launch(void* const* d_in, const int* in_sizes, int n_in,
                              void* d_out, int out_size, void* d_ws, size_t ws_size,
                              hipStream_t stream)
{
    const float* x_in = (const float*)d_in[0];
    const float* h    = (const float*)d_in[1];
    const float* c    = (const float*)d_in[2];
    const float* tau  = (const float*)d_in[3];
    const float* W_x  = (const float*)d_in[4];
    const float* W_ig = (const float*)d_in[5];
    const float* W_q  = (const float*)d_in[6];
    const float* W_k  = (const float*)d_in[7];
    const float* W_v  = (const float*)d_in[8];
    const float* Wi_a = (const float*)d_in[9];
    const float* Wi_x = (const float*)d_in[10];
    const float* b_i  = (const float*)d_in[11];
    const float* Wf_a = (const float*)d_in[12];
    const float* Wf_x = (const float*)d_in[13];
    const float* b_f  = (const float*)d_in[14];
    const float* Wg_a = (const float*)d_in[15];
    const float* Wg_x = (const float*)d_in[16];
    const float* b_g  = (const float*)d_in[17];
    const float* Wo_a = (const float*)d_in[18];
    const float* Wo_x = (const float*)d_in[19];
    const float* b_o  = (const float*)d_in[20];
    float* out = (float*)d_out;

    // Workspace (bf16 elements), total 34,496,512 B (~32.9 MB)
    __hip_bfloat16* wsb = (__hip_bfloat16*)d_ws;
    __hip_bfloat16* xhT = wsb;                        // 16*2304*128 = 4,718,592
    __hip_bfloat16* qa  = xhT + (size_t)4718592;      // 16*2304*64  = 2,359,296
    __hip_bfloat16* kT  = qa  + (size_t)2359296;      // 16*2116*64  = 2,166,784
    __hip_bfloat16* vv  = kT  + (size_t)2166784;      // 16*64*2120  = 2,170,880
    __hip_bfloat16* Wr  = vv  + (size_t)2170880;      // 7*589824    = 4,128,768
    __hip_bfloat16* Wa  = Wr  + (size_t)4128768;      // 4*32768     =   131,072
    __hip_bfloat16* Wp  = Wa  + (size_t)131072;       // 512*768     =   393,216
    __hip_bfloat16* xiT = Wp  + (size_t)393216;       // 2*2304*256  = 1,179,648

    dim3 blk(256);
    prep_kernel<<<dim3(18176), blk, 0, stream>>>(
        W_q, W_k, W_v, Wi_x, Wf_x, Wg_x, Wo_x, Wi_a, Wf_a, Wg_a, Wo_a,
        W_x, W_ig, Wr, Wa, Wp);
    xpose_kernel<<<dim3(144, NB), blk, 0, stream>>>(x_in, h, xiT, xhT);
    proj_mfma_kernel<<<dim3(192), blk, 0, stream>>>(xiT, Wp, xhT);
    conv_qkv_kernel<<<dim3(576), blk, 0, stream>>>(xhT, Wr, qa, kT, vv);
    attn_kernel<<<dim3(576), blk, 0, stream>>>(qa, kT, vv, tau);
    gates_kernel<<<dim3(768), blk, 0, stream>>>(
        xhT, qa, c, Wr, Wa, b_i, b_f, b_g, b_o, out);
}